// Round 7
// baseline (85.700 us; speedup 1.0000x reference)
//
#include <hip/hip_runtime.h>
#include <math.h>

#define BB 4
#define S 8192
#define C 256
#define NW 2048
#define WS 256
#define PSZ 256
#define DD 32
#define KK 65
#define TOTW (BB * NW) /* 8192 */

#define KC 64
#define LDA 68  /* 64 + 4 pad, keeps 16B alignment (68*4=272=17*16) */
#define NBKT 64                 /* position buckets per batch (128 rows each) */
#define TBKT (BB * NBKT)        /* 256 total buckets */

// ---------------------------------------------------------------------------
// Kernel 0: pack B [256 k][512 cols] = [ Wp^T | Wa ]; block 0 zeroes the
// bucket counters (stream-ordered before the histogram).
// ---------------------------------------------------------------------------
__global__ __launch_bounds__(256) void prep_B(const float* __restrict__ Wp,
                                              const float* __restrict__ Wa,
                                              float* __restrict__ Bp,
                                              int* __restrict__ cnt) {
    const int k = blockIdx.x;
    const int t = threadIdx.x;
    Bp[k * 512 + t] = Wp[t * WS + k];
    Bp[k * 512 + 256 + t] = Wa[k * C + t];
    if (k == 0) cnt[t] = 0;
}

// ---------------------------------------------------------------------------
// Kernel 1: f32 blocked GEMM  C[8192 x 512] = ct[8192 x 256] @ B[256 x 512].
// bn 4..7 -> g. bn 0..3 (h cols): fused p_t partial reduction (no h buffer).
// ---------------------------------------------------------------------------
__global__ __launch_bounds__(256, 4) void precomp_gemm(const float* __restrict__ ct,
                                                       const float* __restrict__ Bp,
                                                       const float* __restrict__ Vp,
                                                       float* __restrict__ ptpart,
                                                       float* __restrict__ g) {
    __shared__ __align__(16) float Al[KC][LDA];
    __shared__ __align__(16) float Bl[KC][LDA];

    const int t = threadIdx.x;
    const int bm = blockIdx.x >> 3;       // 0..127
    const int bn = blockIdx.x & 7;        // 0..7
    const int tm = t >> 4;                // 0..15
    const int tn = t & 15;                // 0..15
    const int sm = t >> 2;                // 0..63
    const int sf = t & 3;                 // 0..3

    const float4* ct4 = (const float4*)ct;   // [8192][64]
    const float4* B4  = (const float4*)Bp;   // [256][128]

    float acc[4][4] = {{0.f}};

    for (int kc = 0; kc < 256; kc += KC) {
        __syncthreads();
#pragma unroll
        for (int i = 0; i < 4; i++) {
            const float4 a = ct4[(size_t)(bm * 64 + sm) * 64 + (kc >> 2) + sf + i * 4];
            const int kl = (sf + i * 4) * 4;
            Al[kl + 0][sm] = a.x;
            Al[kl + 1][sm] = a.y;
            Al[kl + 2][sm] = a.z;
            Al[kl + 3][sm] = a.w;
        }
#pragma unroll
        for (int i = 0; i < 4; i++) {
            const float4 b = B4[(size_t)(kc + sm) * 128 + bn * 16 + sf + i * 4];
            *(float4*)&Bl[sm][(sf + i * 4) * 4] = b;
        }
        __syncthreads();

#pragma unroll 8
        for (int kk = 0; kk < KC; kk++) {
            const float4 a = *(const float4*)&Al[kk][tm * 4];
            const float4 b = *(const float4*)&Bl[kk][tn * 4];
            acc[0][0] = fmaf(a.x, b.x, acc[0][0]);
            acc[0][1] = fmaf(a.x, b.y, acc[0][1]);
            acc[0][2] = fmaf(a.x, b.z, acc[0][2]);
            acc[0][3] = fmaf(a.x, b.w, acc[0][3]);
            acc[1][0] = fmaf(a.y, b.x, acc[1][0]);
            acc[1][1] = fmaf(a.y, b.y, acc[1][1]);
            acc[1][2] = fmaf(a.y, b.z, acc[1][2]);
            acc[1][3] = fmaf(a.y, b.w, acc[1][3]);
            acc[2][0] = fmaf(a.z, b.x, acc[2][0]);
            acc[2][1] = fmaf(a.z, b.y, acc[2][1]);
            acc[2][2] = fmaf(a.z, b.z, acc[2][2]);
            acc[2][3] = fmaf(a.z, b.w, acc[2][3]);
            acc[3][0] = fmaf(a.w, b.x, acc[3][0]);
            acc[3][1] = fmaf(a.w, b.y, acc[3][1]);
            acc[3][2] = fmaf(a.w, b.z, acc[3][2]);
            acc[3][3] = fmaf(a.w, b.w, acc[3][3]);
        }
    }

    if (bn >= 4) {
        const int col = bn * 64 + tn * 4 - 256;
#pragma unroll
        for (int i = 0; i < 4; i++) {
            const int row = bm * 64 + tm * 4 + i;
            *(float4*)&g[(size_t)row * 256 + col] =
                make_float4(acc[i][0], acc[i][1], acc[i][2], acc[i][3]);
        }
    } else {
        const float4 vp4 = ((const float4*)Vp)[bn * 16 + tn];
#pragma unroll
        for (int i = 0; i < 4; i++) {
            float v = tanhf(acc[i][0]) * vp4.x;
            v = fmaf(tanhf(acc[i][1]), vp4.y, v);
            v = fmaf(tanhf(acc[i][2]), vp4.z, v);
            v = fmaf(tanhf(acc[i][3]), vp4.w, v);
#pragma unroll
            for (int off = 8; off >= 1; off >>= 1) v += __shfl_xor(v, off);
            if (tn == 0) {
                const int row = bm * 64 + tm * 4 + i;
                ptpart[row * 4 + bn] = v;
            }
        }
    }
}

// ---------------------------------------------------------------------------
// Kernel 2: finalize p_t + position histogram.
// ---------------------------------------------------------------------------
__global__ __launch_bounds__(256) void pt_hist(const float* __restrict__ ptpart,
                                               float* __restrict__ pt,
                                               int* __restrict__ cnt) {
    const int wg = blockIdx.x * 256 + threadIdx.x;
    const float4 pp = ((const float4*)ptpart)[wg];
    const float x = (pp.x + pp.y) + (pp.z + pp.w);
    const float p = (float)S / (1.f + expf(-x));
    pt[wg] = p;
    const int s0 = (int)p;
    const int bkt = (wg >> 11) * NBKT + min(NBKT - 1, max(0, s0 >> 7));
    atomicAdd(&cnt[bkt], 1);
}

// ---------------------------------------------------------------------------
// Kernel 3: exclusive scan of 256 bucket counts -> scatter cursors.
// ---------------------------------------------------------------------------
__global__ __launch_bounds__(256) void scan_kernel(const int* __restrict__ cnt,
                                                   int* __restrict__ offs) {
    __shared__ int sh[TBKT];
    const int t = threadIdx.x;
    const int v = cnt[t];
    sh[t] = v;
    __syncthreads();
    for (int d = 1; d < TBKT; d <<= 1) {
        const int x = (t >= d) ? sh[t - d] : 0;
        __syncthreads();
        sh[t] += x;
        __syncthreads();
    }
    offs[t] = sh[t] - v;   // exclusive
}

// ---------------------------------------------------------------------------
// Kernel 4: scatter window ids into position-sorted permutation.
// ---------------------------------------------------------------------------
__global__ __launch_bounds__(256) void scatter_kernel(const float* __restrict__ pt,
                                                      int* __restrict__ offs,
                                                      int* __restrict__ perm) {
    const int wg = blockIdx.x * 256 + threadIdx.x;
    const int s0 = (int)pt[wg];
    const int bkt = (wg >> 11) * NBKT + min(NBKT - 1, max(0, s0 >> 7));
    const int pos = atomicAdd(&offs[bkt], 1);
    perm[pos] = wg;
}

// ---------------------------------------------------------------------------
// Kernel 5: gather-attention v3. R6 lesson: loop was latency-bound (VALUBusy
// 34%) on {load -> 16-deep fmaf chain -> 4 shuffles -> exps}. v3: (a) each
// group PREFETCHES its next q-row (clamped, always in-bounds) so the load
// overlaps a full iteration of compute; (b) dot product split into 4
// parallel partials (dep depth 64 -> ~20 cyc). VGPR ~52: still under the
// 64-reg occupancy step, unlike R3's failed prefetch.
// ---------------------------------------------------------------------------
__global__ __launch_bounds__(256) void attn(const float* __restrict__ q,
                                            const float* __restrict__ g,
                                            const float* __restrict__ pt,
                                            const int* __restrict__ perm,
                                            float* __restrict__ out) {
    const int tid = threadIdx.x;
    const int lane = tid & 63;
    const int wv = tid >> 6;
    const int bid = blockIdx.x;
    const int sb = (bid & 7) * 256 + (bid >> 3);   // XCD-chunked sorted order
    const int wg = perm[sb * 4 + wv];
    const int b = wg >> 11;                    // NW = 2048
    const int grp = lane >> 4;                 // key sub-slot
    const int sub = lane & 15;                 // channel group

    const float p = pt[wg];
    const int s0 = (int)p;                     // trunc == floor (p > 0)

    const float* grow = g + (size_t)wg * C + sub * 4;
    const float4 g0 = *(const float4*)(grow);
    const float4 g1 = *(const float4*)(grow + 64);
    const float4 g2 = *(const float4*)(grow + 128);
    const float4 g3 = *(const float4*)(grow + 192);

    const float* qb = q + (size_t)b * S * C + sub * 4;

    float m = -1e30f, den = 0.f;
    float4 a0 = {0, 0, 0, 0}, a1 = {0, 0, 0, 0}, a2 = {0, 0, 0, 0}, a3 = {0, 0, 0, 0};

    // prime the pipeline: key k = grp
    int s = s0 + grp - DD;
    const float* qr = qb + (size_t)min(max(s, 0), S - 1) * C;
    float4 q0 = *(const float4*)(qr);
    float4 q1 = *(const float4*)(qr + 64);
    float4 q2 = *(const float4*)(qr + 128);
    float4 q3 = *(const float4*)(qr + 192);

    for (int it = 0; it < 17; it++) {
        const int k = it * 4 + grp;
        const bool valid = (k <= 64) && ((unsigned)s < (unsigned)S);

        // prefetch next key's row (clamped -> always safe; dead on last iter)
        const int sn = s + 4;
        const float* qn = qb + (size_t)min(max(sn, 0), S - 1) * C;
        const float4 n0 = *(const float4*)(qn);
        const float4 n1 = *(const float4*)(qn + 64);
        const float4 n2 = *(const float4*)(qn + 128);
        const float4 n3 = *(const float4*)(qn + 192);

        // 4 parallel dot partials
        float d0 = q0.x * g0.x, d1 = q1.x * g1.x, d2 = q2.x * g2.x, d3 = q3.x * g3.x;
        d0 = fmaf(q0.y, g0.y, d0); d1 = fmaf(q1.y, g1.y, d1);
        d2 = fmaf(q2.y, g2.y, d2); d3 = fmaf(q3.y, g3.y, d3);
        d0 = fmaf(q0.z, g0.z, d0); d1 = fmaf(q1.z, g1.z, d1);
        d2 = fmaf(q2.z, g2.z, d2); d3 = fmaf(q3.z, g3.z, d3);
        d0 = fmaf(q0.w, g0.w, d0); d1 = fmaf(q1.w, g1.w, d1);
        d2 = fmaf(q2.w, g2.w, d2); d3 = fmaf(q3.w, g3.w, d3);
        float d = (d0 + d1) + (d2 + d3);
#pragma unroll
        for (int off = 8; off >= 1; off >>= 1) d += __shfl_xor(d, off);

        d = valid ? d : -3e38f;

        const float fs = (float)s - p;
        const float tt = fs * (1.f / (float)DD);
        const float lg = -2.f * tt * tt;

        const float mn = fmaxf(m, d);
        const float sc = __expf(m - mn);       // rescale old state
        const float e  = __expf(d - mn);       // denominator term
        const float eg = __expf(d - mn + lg);  // numerator term (exp * gauss)
        den = fmaf(den, sc, e);
        m = mn;

        a0.x = fmaf(eg, q0.x, a0.x * sc); a0.y = fmaf(eg, q0.y, a0.y * sc);
        a0.z = fmaf(eg, q0.z, a0.z * sc); a0.w = fmaf(eg, q0.w, a0.w * sc);
        a1.x = fmaf(eg, q1.x, a1.x * sc); a1.y = fmaf(eg, q1.y, a1.y * sc);
        a1.z = fmaf(eg, q1.z, a1.z * sc); a1.w = fmaf(eg, q1.w, a1.w * sc);
        a2.x = fmaf(eg, q2.x, a2.x * sc); a2.y = fmaf(eg, q2.y, a2.y * sc);
        a2.z = fmaf(eg, q2.z, a2.z * sc); a2.w = fmaf(eg, q2.w, a2.w * sc);
        a3.x = fmaf(eg, q3.x, a3.x * sc); a3.y = fmaf(eg, q3.y, a3.y * sc);
        a3.z = fmaf(eg, q3.z, a3.z * sc); a3.w = fmaf(eg, q3.w, a3.w * sc);

        q0 = n0; q1 = n1; q2 = n2; q3 = n3;
        s = sn;
    }

    // merge the 4 groups (cross-lane butterfly; m/den uniform within group)
    float M = m;
    M = fmaxf(M, __shfl_xor(M, 16));
    M = fmaxf(M, __shfl_xor(M, 32));
    const float scg = __expf(m - M);

    den *= scg;
    den += __shfl_xor(den, 16);
    den += __shfl_xor(den, 32);

#define MERGE(v) { v *= scg; v += __shfl_xor(v, 16); v += __shfl_xor(v, 32); }
    MERGE(a0.x) MERGE(a0.y) MERGE(a0.z) MERGE(a0.w)
    MERGE(a1.x) MERGE(a1.y) MERGE(a1.z) MERGE(a1.w)
    MERGE(a2.x) MERGE(a2.y) MERGE(a2.z) MERGE(a2.w)
    MERGE(a3.x) MERGE(a3.y) MERGE(a3.z) MERGE(a3.w)
#undef MERGE

    float4 o = a0;
    if (grp == 1) o = a1;
    else if (grp == 2) o = a2;
    else if (grp == 3) o = a3;

    const float r = 1.f / den;
    o.x *= r; o.y *= r; o.z *= r; o.w *= r;

    *(float4*)(out + (size_t)wg * C + lane * 4) = o;
}

// ---------------------------------------------------------------------------
extern "C" void kernel_launch(void* const* d_in, const int* in_sizes, int n_in,
                              void* d_out, int out_size, void* d_ws, size_t ws_size,
                              hipStream_t stream) {
    const float* q  = (const float*)d_in[0];
    const float* ct = (const float*)d_in[1];
    const float* Wa = (const float*)d_in[2];
    const float* Wp = (const float*)d_in[3];
    const float* Vp = (const float*)d_in[4];
    float* out = (float*)d_out;

    char* ws = (char*)d_ws;
    float* Bp     = (float*)ws;                   // 512 KB
    float* ptpart = (float*)(ws + 524288);        // 128 KB
    float* pt     = (float*)(ws + 655360);        // 32 KB
    int*   cnt    = (int*)  (ws + 688128);        // 1 KB
    int*   offs   = (int*)  (ws + 689152);        // 1 KB
    int*   perm   = (int*)  (ws + 690176);        // 32 KB
    float* g      = (float*)(ws + 722944);        // 8 MB

    prep_B<<<256, 256, 0, stream>>>(Wp, Wa, Bp, cnt);
    precomp_gemm<<<1024, 256, 0, stream>>>(ct, Bp, Vp, ptpart, g);
    pt_hist<<<TOTW / 256, 256, 0, stream>>>(ptpart, pt, cnt);
    scan_kernel<<<1, TBKT, 0, stream>>>(cnt, offs);
    scatter_kernel<<<TOTW / 256, 256, 0, stream>>>(pt, offs, perm);
    attn<<<TOTW / 4, 256, 0, stream>>>(q, g, pt, perm, out);
}